// Round 3
// baseline (361.165 us; speedup 1.0000x reference)
//
#include <hip/hip_runtime.h>
#include <cstdint>

#define ROW_LEN 4096
#define KSEL 8
#define NT 256
#define EPT 16   // thread t owns row indices [t*16, t*16+16)

// compare-exchange descending on array a
#define CEDA(a, i, j) { float x_ = a[i], y_ = a[j]; a[i] = fmaxf(x_, y_); a[j] = fminf(x_, y_); }

// Batcher odd-even sort-8 descending (19 CE), elements a[o..o+7]
#define SORT8D(a, o) \
    CEDA(a,o+0,o+1) CEDA(a,o+2,o+3) CEDA(a,o+4,o+5) CEDA(a,o+6,o+7) \
    CEDA(a,o+0,o+2) CEDA(a,o+1,o+3) CEDA(a,o+4,o+6) CEDA(a,o+5,o+7) \
    CEDA(a,o+1,o+2) CEDA(a,o+5,o+6) \
    CEDA(a,o+0,o+4) CEDA(a,o+1,o+5) CEDA(a,o+2,o+6) CEDA(a,o+3,o+7) \
    CEDA(a,o+2,o+4) CEDA(a,o+3,o+5) \
    CEDA(a,o+1,o+2) CEDA(a,o+3,o+4) CEDA(a,o+5,o+6)

// bitonic-merge-8 descending (12 CE): input bitonic, output sorted desc
#define BMERGE8D(a) \
    CEDA(a,0,4) CEDA(a,1,5) CEDA(a,2,6) CEDA(a,3,7) \
    CEDA(a,0,2) CEDA(a,1,3) CEDA(a,4,6) CEDA(a,5,7) \
    CEDA(a,0,1) CEDA(a,2,3) CEDA(a,4,5) CEDA(a,6,7)

__global__ __launch_bounds__(NT) void kmax_kernel(const float* __restrict__ in,
                                                  float* __restrict__ out) {
    const int row  = blockIdx.x;
    const int tid  = threadIdx.x;
    const int lane = tid & 63;
    const int wave = tid >> 6;

    const float4* p4 = reinterpret_cast<const float4*>(in + (size_t)row * ROW_LEN + (size_t)tid * EPT);

    float k[EPT];
#pragma unroll
    for (int j = 0; j < 4; ++j) {
        float4 a = p4[j];
        k[j * 4 + 0] = a.x;
        k[j * 4 + 1] = a.y;
        k[j * 4 + 2] = a.z;
        k[j * 4 + 3] = a.w;
    }

    // ---- per-thread sorted (desc) top-8 of 16 ----
    float t[EPT];
#pragma unroll
    for (int s = 0; s < EPT; ++s) t[s] = k[s];
    SORT8D(t, 0)
    SORT8D(t, 8)
#pragma unroll
    for (int s = 0; s < 8; ++s) t[s] = fmaxf(t[s], t[15 - s]);  // bitonic top-8 of 16
    BMERGE8D(t)

    // ---- wave-level: log-tree merge of 64 sorted lists, zero barriers ----
#pragma unroll
    for (int off = 1; off < 64; off <<= 1) {
        float o[8];
#pragma unroll
        for (int s = 0; s < 8; ++s) o[s] = __shfl_xor(t[s], off, 64);
#pragma unroll
        for (int s = 0; s < 8; ++s) t[s] = fmaxf(t[s], o[7 - s]);
        BMERGE8D(t)
    }
    // every lane now holds the wave's sorted-desc top-8

    __shared__ float    W[4][KSEL];
    __shared__ unsigned swsum[4];

    if (lane == 0) {
        float4* wp = reinterpret_cast<float4*>(&W[wave][0]);
        wp[0] = make_float4(t[0], t[1], t[2], t[3]);
        wp[1] = make_float4(t[4], t[5], t[6], t[7]);
    }
    __syncthreads();

    // ---- cross-wave (redundant in every thread): T = 8th largest of block ----
    float A[8], B[8];
#pragma unroll
    for (int s = 0; s < 8; ++s) A[s] = fmaxf(W[0][s], W[1][7 - s]);
    BMERGE8D(A)
#pragma unroll
    for (int s = 0; s < 8; ++s) B[s] = fmaxf(W[2][s], W[3][7 - s]);
    BMERGE8D(B)
    // 8th largest of (A ∪ B) = min over s of max(A[s], B[7-s])
    float T = fmaxf(A[0], B[7]);
#pragma unroll
    for (int s = 1; s < 8; ++s) T = fminf(T, fmaxf(A[s], B[7 - s]));

    // ---- gather: (k > T) plus first (8 - total_gt) elements == T in index order ----
    int cgt = 0, ceq = 0;
#pragma unroll
    for (int s = 0; s < EPT; ++s) {
        cgt += (k[s] > T);
        ceq += (k[s] == T);
    }
    unsigned packed = ((unsigned)cgt << 16) | (unsigned)ceq;
    unsigned p = packed;  // inclusive prefix within wave
#pragma unroll
    for (int off = 1; off < 64; off <<= 1) {
        unsigned o = (unsigned)__shfl_up((int)p, off, 64);
        if (lane >= off) p += o;
    }
    if (lane == 63) swsum[wave] = p;
    __syncthreads();
    unsigned basep = 0, total = 0;
#pragma unroll
    for (int w = 0; w < 4; ++w) {
        unsigned ws = swsum[w];
        total += ws;
        if (w < wave) basep += ws;
    }
    unsigned excl  = basep + p - packed;
    int totgt = (int)(total >> 16), toteq = (int)(total & 0xFFFFu);
    int pgt   = (int)(excl  >> 16), peq   = (int)(excl  & 0xFFFFu);
    int Q      = KSEL - totgt;                  // # of ==T elements to take (>=1)
    int mybase = pgt + (peq < Q ? peq : Q);
    float* op  = out + (size_t)row * KSEL + mybase;

    if (totgt + toteq == KSEL) {
#pragma unroll
        for (int s = 0; s < EPT; ++s) {
            if (k[s] >= T) { *op++ = k[s]; }
        }
    } else {
        int myq = Q - peq; myq = myq < 0 ? 0 : myq;
        int eqSeen = 0;
#pragma unroll
        for (int s = 0; s < EPT; ++s) {
            bool iseq = (k[s] == T);
            bool sel  = (k[s] > T) || (iseq && (eqSeen < myq));
            eqSeen += iseq;
            if (sel) { *op++ = k[s]; }
        }
    }
}

extern "C" void kernel_launch(void* const* d_in, const int* in_sizes, int n_in,
                              void* d_out, int out_size, void* d_ws, size_t ws_size,
                              hipStream_t stream) {
    const float* in  = (const float*)d_in[0];
    float*       out = (float*)d_out;
    const int rows = in_sizes[0] / ROW_LEN;  // 32*512 = 16384
    kmax_kernel<<<rows, NT, 0, stream>>>(in, out);
}

// Round 4
// 354.174 us; speedup vs baseline: 1.0197x; 1.0197x over previous
//
#include <hip/hip_runtime.h>
#include <cstdint>

#define ROW_LEN 4096
#define KSEL 8
#define NT 256
#define EPT 16          // thread t owns row indices [t*16, t*16+16)
#define C0 2.30f        // P(N(0,1) > 2.30) ~ 0.0107 -> ~44 candidates per 4096-row
#define CANDCAP 128

// order-preserving fp32 -> u32 (monotone; no NaN in input)
__device__ inline unsigned ordkey(float f) {
    int t = __float_as_int(f);
    return (unsigned)(t ^ ((t >> 31) | 0x80000000));
}
__device__ inline float unkey(unsigned u) {
    int t = (int)u;
    return __int_as_float(t < 0 ? (t ^ 0x80000000) : ~t);
}

__global__ __launch_bounds__(NT) void kmax_kernel(const float* __restrict__ in,
                                                  float* __restrict__ out) {
    const int row  = blockIdx.x;
    const int tid  = threadIdx.x;
    const int lane = tid & 63;
    const int wave = tid >> 6;

    __shared__ float    cand[CANDCAP];
    __shared__ int      scnt;
    __shared__ unsigned swsum[4];

    if (tid == 0) scnt = 0;

    const float4* p4 = reinterpret_cast<const float4*>(in + (size_t)row * ROW_LEN + (size_t)tid * EPT);
    float k[EPT];
#pragma unroll
    for (int j = 0; j < 4; ++j) {
        float4 a = p4[j];
        k[j * 4 + 0] = a.x;
        k[j * 4 + 1] = a.y;
        k[j * 4 + 2] = a.z;
        k[j * 4 + 3] = a.w;
    }
    __syncthreads();  // scnt initialized

    // ---- phase 1: filter candidates > C0 into LDS ----
#pragma unroll
    for (int s = 0; s < EPT; ++s) {
        if (k[s] > C0) {
            int pos = atomicAdd(&scnt, 1);
            if (pos < CANDCAP) cand[pos] = k[s];
        }
    }
    __syncthreads();

    const int cnt = scnt;
    unsigned Tkey;
    if (cnt >= KSEL && cnt <= CANDCAP) {
        // ---- phase 2 (common): exact 8th-largest key via ballot bit-descent ----
        float f0 = cand[lane];          // reads of uninit slots are masked below
        float f1 = cand[lane + 64];
        unsigned c0 = (lane      < cnt) ? ordkey(f0) : 0u;
        unsigned c1 = (lane + 64 < cnt) ? ordkey(f1) : 0u;
        unsigned T = 0;
#pragma unroll
        for (int b = 31; b >= 0; --b) {
            unsigned c = T | (1u << b);
            int n = __popcll(__ballot(c0 >= c)) + __popcll(__ballot(c1 >= c));
            if (n >= KSEL) T = c;   // wave-uniform
        }
        Tkey = T;
    } else {
        // ---- fallback (never on this input, exact in general): block-wide bit-descent ----
        unsigned kk[EPT];
#pragma unroll
        for (int s = 0; s < EPT; ++s) kk[s] = ordkey(k[s]);
        unsigned T = 0;
        for (int b = 31; b >= 0; --b) {
            unsigned c = T | (1u << b);
            int n = 0;
#pragma unroll
            for (int s = 0; s < EPT; ++s) n += __popcll(__ballot(kk[s] >= c));
            if (lane == 0) swsum[wave] = (unsigned)n;
            __syncthreads();
            n = (int)(swsum[0] + swsum[1] + swsum[2] + swsum[3]);
            __syncthreads();
            if (n >= KSEL) T = c;
        }
        Tkey = T;
    }
    const float T = unkey(Tkey);

    // ---- phase 3: gather (k > T) plus first (8 - totgt) elements == T, index order ----
    int cgt = 0, ceq = 0;
#pragma unroll
    for (int s = 0; s < EPT; ++s) {
        cgt += (k[s] > T);
        ceq += (k[s] == T);
    }
    // wave-level exclusive prefix + totals via bit-plane ballots (no DS shuffles)
    const unsigned long long lt = (1ull << lane) - 1ull;
    int exGt = 0, totGt = 0;
#pragma unroll
    for (int b = 0; b < 3; ++b) {   // cgt <= 7 (at most 7 elements strictly > T)
        unsigned long long m = __ballot((cgt >> b) & 1);
        exGt  += __popcll(m & lt) << b;
        totGt += __popcll(m) << b;
    }
    int exEq = 0, totEq = 0;
#pragma unroll
    for (int b = 0; b < 5; ++b) {   // ceq <= 16
        unsigned long long m = __ballot((ceq >> b) & 1);
        exEq  += __popcll(m & lt) << b;
        totEq += __popcll(m) << b;
    }
    if (lane == 0) swsum[wave] = ((unsigned)totGt << 16) | (unsigned)totEq;
    __syncthreads();
    unsigned base = 0, tot = 0;
#pragma unroll
    for (int w = 0; w < 4; ++w) {
        unsigned v = swsum[w];
        tot += v;
        if (w < wave) base += v;
    }
    const int totgt = (int)(tot >> 16), toteq = (int)(tot & 0xFFFFu);
    const int pgt = (int)(base >> 16) + exGt;
    const int peq = (int)(base & 0xFFFFu) + exEq;
    const int Q = KSEL - totgt;                 // # of ==T elements to take (>=1)
    const int mybase = pgt + (peq < Q ? peq : Q);
    float* op = out + (size_t)row * KSEL + mybase;

    if (totgt + toteq == KSEL) {
#pragma unroll
        for (int s = 0; s < EPT; ++s) {
            if (k[s] >= T) { *op++ = k[s]; }
        }
    } else {
        int myq = Q - peq; myq = myq < 0 ? 0 : myq;
        int eqSeen = 0;
#pragma unroll
        for (int s = 0; s < EPT; ++s) {
            bool iseq = (k[s] == T);
            bool sel  = (k[s] > T) || (iseq && (eqSeen < myq));
            eqSeen += iseq;
            if (sel) { *op++ = k[s]; }
        }
    }
}

extern "C" void kernel_launch(void* const* d_in, const int* in_sizes, int n_in,
                              void* d_out, int out_size, void* d_ws, size_t ws_size,
                              hipStream_t stream) {
    const float* in  = (const float*)d_in[0];
    float*       out = (float*)d_out;
    const int rows = in_sizes[0] / ROW_LEN;  // 32*512 = 16384
    kmax_kernel<<<rows, NT, 0, stream>>>(in, out);
}